// Round 1
// 307.175 us; speedup vs baseline: 1.0135x; 1.0135x over previous
//
#include <hip/hip_runtime.h>

// PatchEmbedder: out[b,p,:] = patch_mask[b,p] ? sum_n sum_l mask_n[b,p,l]*emb_n[ids_n[b,p,l],:] : 0
// B=8, P=1024, D=512, L=(8,7,6).
//
// v2 (latency-bound fix): TWO waves per patch, each owning a 1024-B half-row
// (one float4 per lane). All 21 gathers are staged into registers BEFORE any
// accumulation -> up to 21 global_load_dwordx4 in flight per wave instead of
// stalling on vmcnt every add. ids/masks/pmask are wave-uniform: readfirstlane
// moves them to SGPRs so masked-off ids are skipped with a scalar branch and
// gather addresses are SGPR-base + one shared VGPR offset.
// 16384 waves (vs 8192) also backfills the ~50% of waves that exit early on
// patch_mask==0, keeping occupancy up mid-kernel.

#define D_DIM   512
#define NPATCH  8192            // B*P
#define NWAVES  (NPATCH * 2)    // 2 half-row waves per patch

__device__ __forceinline__ void acc_add(float4& a, const float4 b) {
    a.x += b.x; a.y += b.y; a.z += b.z; a.w += b.w;
}

template <int L>
__device__ __forceinline__ void gather_stage(const int* __restrict__ ids,
                                             const int* __restrict__ mask,
                                             const float* __restrict__ emb,
                                             int foff, float4* __restrict__ t) {
#pragma unroll
    for (int l = 0; l < L; ++l) {
        // mask/ids are identical across the wave: force SGPR so the guard is a
        // scalar branch (s_cmp/s_cbranch, no exec churn) and the row base is
        // scalar address math.
        if (__builtin_amdgcn_readfirstlane(mask[l])) {
            const int sid = __builtin_amdgcn_readfirstlane(ids[l]);
            t[l] = *(const float4*)(emb + (size_t)sid * D_DIM + foff);
        }
    }
}

__global__ __launch_bounds__(256) void patch_embed_kernel(
    const int* __restrict__ ids1, const int* __restrict__ m1, const float* __restrict__ e1,
    const int* __restrict__ ids2, const int* __restrict__ m2, const float* __restrict__ e2,
    const int* __restrict__ ids3, const int* __restrict__ m3, const float* __restrict__ e3,
    const int* __restrict__ pmask, float* __restrict__ out) {
    const int lane = threadIdx.x & 63;
    const int gw   = (blockIdx.x << 2) | (threadIdx.x >> 6);     // global wave id
    const int patch = __builtin_amdgcn_readfirstlane(gw >> 1);   // 2 waves/patch
    const int foff  = ((gw & 1) << 8) | (lane << 2);             // float offset in row

    // Staging registers: 21 float4 = 84 VGPRs, all loads issued before any sum.
    float4 t[21];
#pragma unroll
    for (int i = 0; i < 21; ++i) t[i] = make_float4(0.f, 0.f, 0.f, 0.f);

    if (__builtin_amdgcn_readfirstlane(pmask[patch])) {   // wave-uniform, scalar branch
        gather_stage<8>(ids1 + patch * 8, m1 + patch * 8, e1, foff, t);
        gather_stage<7>(ids2 + patch * 7, m2 + patch * 7, e2, foff, t + 8);
        gather_stage<6>(ids3 + patch * 6, m3 + patch * 6, e3, foff, t + 15);
    }

    // Reduce after all loads are in flight; compiler interleaves waits with adds.
    float4 acc = t[0];
#pragma unroll
    for (int i = 1; i < 21; ++i) acc_add(acc, t[i]);

    *(float4*)(out + (size_t)patch * D_DIM + foff) = acc;
}

extern "C" void kernel_launch(void* const* d_in, const int* in_sizes, int n_in,
                              void* d_out, int out_size, void* d_ws, size_t ws_size,
                              hipStream_t stream) {
    // setup_inputs() dict order:
    // 0 ids_1[8,1024,8] i64->int, 1 mask_1[8,1024,8] bool->int, 2 emb_1[65536,512] f32,
    // 3 ids_2[8,1024,7],          4 mask_2[8,1024,7],           5 emb_2[65536,512],
    // 6 ids_3[8,1024,6],          7 mask_3[8,1024,6],           8 emb_3[65536,512],
    // 9 patch_mask[8,1024] bool->int
    const int*   ids1  = (const int*)d_in[0];
    const int*   m1    = (const int*)d_in[1];
    const float* e1    = (const float*)d_in[2];
    const int*   ids2  = (const int*)d_in[3];
    const int*   m2    = (const int*)d_in[4];
    const float* e2    = (const float*)d_in[5];
    const int*   ids3  = (const int*)d_in[6];
    const int*   m3    = (const int*)d_in[7];
    const float* e3    = (const float*)d_in[8];
    const int*   pmask = (const int*)d_in[9];
    float* out = (float*)d_out;

    dim3 grid(NWAVES / 4);   // 4096 blocks x 4 waves = 16384 waves = 2 per patch
    dim3 block(256);
    patch_embed_kernel<<<grid, block, 0, stream>>>(ids1, m1, e1, ids2, m2, e2,
                                                   ids3, m3, e3, pmask, out);
}